// Round 19
// baseline (237.566 us; speedup 1.0000x reference)
//
#include <hip/hip_runtime.h>
#include <math.h>

constexpr int IN_CH = 256;
constexpr int HID   = 128;
constexpr int LAT   = 64;

constexpr int SBN    = 1024;    // nodes per super-bucket
constexpr int SB_CAP = 18432;   // edges per SB region: mean 16384, +16 sigma
constexpr int EPB    = 8192;    // edges per bin block
constexpr int HCAP   = 9472;    // per-half-SB LDS staging: mean 8192, +14 sigma

typedef unsigned short u16;
typedef unsigned int   u32;
typedef unsigned char  u8;
typedef __bf16  bf16x8 __attribute__((ext_vector_type(8)));
typedef float   f32x4  __attribute__((ext_vector_type(4)));

__device__ inline u16 f2bf(float f) {
    unsigned u = __float_as_uint(f);
    unsigned r = u + 0x7FFF + ((u >> 16) & 1);
    return (u16)(r >> 16);
}
__device__ inline float bf2f(u16 h) {
    return __uint_as_float((unsigned)h << 16);
}

// direct global->LDS 16B copy; lds base must be wave-uniform (HW: dst = base + lane*16)
__device__ inline void gload_lds16(const u16* g, u16* lds) {
    __builtin_amdgcn_global_load_lds(
        (const __attribute__((address_space(1))) void*)g,
        (__attribute__((address_space(3))) void*)lds,
        16, 0, 0);
}

// ---------------- coalesced-write CSR build ----------------

__global__ void k_zero(int* p, int n) {
    int i = blockIdx.x * blockDim.x + threadIdx.x;
    if (i < n) p[i] = 0;
}

// stage 1: per-block LDS counting sort by super-bucket, then COALESCED run flush.
// Fused tail: x f32 -> (Xh, Xl) bf16 split (streams on idle BW while atomics run).
__launch_bounds__(512)
__global__ void k_bin_sb(const int* __restrict__ esrc, const int* __restrict__ edst,
                         int* __restrict__ sb_fill, u32* __restrict__ sbe,
                         const float* __restrict__ x, u16* __restrict__ Xh,
                         u16* __restrict__ Xl,
                         int E, int NSB, int N) {
    __shared__ u32 sorted[EPB];      // 32 KB
    __shared__ u8  ssb[EPB];         // 8 KB
    __shared__ int cnt[128], sc[128], excl[128], fil[128], off[128];

    const int t  = threadIdx.x;
    const int e0 = blockIdx.x * EPB;

    for (int j = t; j < 128; j += 512) { cnt[j] = 0; fil[j] = 0; }
    __syncthreads();

#pragma unroll
    for (int it = 0; it < EPB / 512; ++it) {
        int e = e0 + it * 512 + t;
        if (e < E) atomicAdd(&cnt[edst[e] >> 10], 1);
    }
    __syncthreads();

    if (t < 128) sc[t] = cnt[t];
    __syncthreads();
#pragma unroll
    for (int o = 1; o < 128; o <<= 1) {
        int u = 0;
        if (t < 128 && t >= o) u = sc[t - o];
        __syncthreads();
        if (t < 128) sc[t] += u;
        __syncthreads();
    }
    if (t < 128) excl[t] = sc[t] - cnt[t];
    if (t < NSB) off[t] = atomicAdd(&sb_fill[t], cnt[t]);
    __syncthreads();

#pragma unroll
    for (int it = 0; it < EPB / 512; ++it) {
        int e = e0 + it * 512 + t;
        if (e < E) {
            int d  = edst[e];
            int sb = d >> 10;
            int pos = excl[sb] + atomicAdd(&fil[sb], 1);
            sorted[pos] = (u32)esrc[e] | ((u32)(d & 1023) << 17);
            ssb[pos]    = (u8)sb;
        }
    }
    __syncthreads();

    int mtot = sc[127];
    for (int i = t; i < mtot; i += 512) {
        int sb = ssb[i];
        int o  = off[sb] + (i - excl[sb]);
        if (o < SB_CAP) sbe[(size_t)sb * SB_CAP + o] = sorted[i];
    }

    // ---- fused x split: 8 f32 -> 8 bf16 hi + 8 bf16 lo per task ----
    const int total = N * (IN_CH / 8);
    const int stride = (int)gridDim.x * 512;
    for (int q = (int)blockIdx.x * 512 + t; q < total; q += stride) {
        int r  = q >> 5;
        int c8 = (q & 31) * 8;
        float f[8];
        *(float4*)&f[0] = *(const float4*)&x[(size_t)r * IN_CH + c8];
        *(float4*)&f[4] = *(const float4*)&x[(size_t)r * IN_CH + c8 + 4];
        u16 hh[8], ll[8];
#pragma unroll
        for (int j = 0; j < 8; ++j) {
            hh[j] = f2bf(f[j]);
            ll[j] = f2bf(f[j] - bf2f(hh[j]));
        }
        *(uint4*)&Xh[(size_t)r * IN_CH + c8] = *(const uint4*)hh;
        *(uint4*)&Xl[(size_t)r * IN_CH + c8] = *(const uint4*)ll;
    }
}

// stage 2: per-half-SB counting sort; streamed passes, LDS staging, coalesced flush.
__launch_bounds__(512)
__global__ void k_sbsort(const int* __restrict__ sb_fill, const u32* __restrict__ sbe,
                         int* __restrict__ csr, int* __restrict__ row_ptr,
                         int* __restrict__ row_end, float* __restrict__ dinv, int N) {
    __shared__ int cnt[SBN];
    __shared__ int exclh[512];
    __shared__ int fillb[512];
    __shared__ int lsrc[HCAP];
    __shared__ int wsum[8];
    __shared__ int sh_h1base, sh_mtot;

    const int t    = threadIdx.x;
    const int sb   = blockIdx.x >> 1;
    const int half = blockIdx.x & 1;
    const int m    = min(sb_fill[sb], SB_CAP);
    const size_t base = (size_t)sb * SB_CAP;
    const int node0 = sb * SBN;

    for (int j = t; j < SBN; j += 512) cnt[j] = 0;
    fillb[t & 511] = 0;
    __syncthreads();

    for (int i = t; i < m; i += 512)
        atomicAdd(&cnt[sbe[base + i] >> 17], 1);
    __syncthreads();

    int c0 = cnt[2 * t], c1 = cnt[2 * t + 1];
    int p  = c0 + c1;
    int lane = t & 63, wid = t >> 6;
    int v = p;
#pragma unroll
    for (int o = 1; o < 64; o <<= 1) {
        int u = __shfl_up(v, o, 64);
        if (lane >= o) v += u;
    }
    if (lane == 63) wsum[wid] = v;
    __syncthreads();
    int woff = 0;
#pragma unroll
    for (int w = 0; w < 8; ++w) if (w < wid) woff += wsum[w];
    int incl = woff + v;
    int eP   = incl - p;
    if (t == 511) sh_mtot = incl;
    if (t == 256) sh_h1base = eP;

#pragma unroll
    for (int q = 0; q < 2; ++q) {
        int j  = 2 * t + q;
        int ex = q ? (eP + c0) : eP;
        int cc = q ? c1 : c0;
        if ((j >> 9) == half) {
            exclh[j & 511] = ex;
            int node = node0 + j;
            if (node < N) {
                row_ptr[node] = (int)base + ex;
                row_end[node] = (int)base + ex + cc;
                dinv[node]    = rsqrtf((float)(cc + 1));   // +1 self-loop
            }
        }
    }
    __syncthreads();

    const int hb = (half == 0) ? 0 : sh_h1base;
    int mh = (half == 0) ? sh_h1base : (sh_mtot - sh_h1base);

    for (int i = t; i < m; i += 512) {
        u32 p2  = sbe[base + i];
        int d10 = p2 >> 17;
        if ((d10 >> 9) == half) {
            int slot = atomicAdd(&fillb[d10 & 511], 1);
            int pos  = exclh[d10 & 511] - hb + slot;
            if (pos < HCAP) lsrc[pos] = (int)(p2 & 0x1FFFF);
        }
    }
    __syncthreads();

    if (mh > HCAP) mh = HCAP;
    for (int i = t; i < mh; i += 512) csr[base + hb + i] = lsrc[i];
}

// ---------------- W split: f32 -> (hi, lo) bf16 ----------------

__global__ void k_split_w(const float* __restrict__ W, u16* __restrict__ Wh,
                          u16* __restrict__ Wl, int n) {
    int i = blockIdx.x * blockDim.x + threadIdx.x;
    if (i < n) {
        float v = W[i];
        u16 h = f2bf(v);
        Wh[i] = h;
        Wl[i] = f2bf(v - bf2f(h));
    }
}

// ---------------- MFMA GEMM with global_load_lds staging ----------------
// h = bf16( (A @ W^T) * dinv[row] ), node-major. All inputs bf16 (A pre-split).
// Staging: per K-step each wave issues 3 (gemm1) / 1-2 (gemm2) global_load_lds
// of 1 KB each — no VGPR round-trip, no staging VALU, linear 64B LDS rows.
// HAS_AL: A has a lo half (x3 MFMA); else x2.

template<int K, int NOUT, bool HAS_AL>
__device__ inline void gemm_body(int bid,
                                 const u16* __restrict__ Ahg,
                                 const u16* __restrict__ Alg,
                                 const u16* __restrict__ Whg,
                                 const u16* __restrict__ Wlg,
                                 const float* __restrict__ dinv,
                                 u16* __restrict__ h_out,
                                 int M) {
    constexpr int BM = 64, BK = 32;
    constexpr int WAVES_N = (NOUT == 128) ? 4 : 2;
    constexpr int WAVES_M = 8 / WAVES_N;         // 2 or 4
    constexpr int WM      = BM / WAVES_M;        // 32 or 16
    constexpr int WN      = NOUT / WAVES_N;      // 32
    constexpr int MF      = WM / 16;             // 2 or 1
    constexpr int NF      = WN / 16;             // 2
    constexpr int AT      = BM / 16;             // 4 tasks per A array
    constexpr int BT      = NOUT / 16;           // 8 or 4 tasks per W array
    constexpr int NA      = AT * (HAS_AL ? 2 : 1);
    constexpr int NT      = NA + 2 * BT;         // 24 (gemm1) / 12 (gemm2)

    __shared__ u16 Ah[BM][BK];
    __shared__ u16 Al[HAS_AL ? BM : 1][BK];
    __shared__ u16 Bh[NOUT][BK], Bl[NOUT][BK];

    const int t    = threadIdx.x;
    const int lane = t & 63;
    const int wid  = t >> 6;
    const int wm   = (wid / WAVES_N) * WM;
    const int wn   = (wid % WAVES_N) * WN;
    const int lr   = lane & 15;
    const int lk   = (lane >> 4) * 8;
    const int row0 = bid * BM;

    const int lrow = lane >> 2;        // 0..15: row within a 16-row task
    const int lch  = (lane & 3) * 8;   // elem offset within a 64B row

    f32x4 acc[MF][NF];
#pragma unroll
    for (int i = 0; i < MF; ++i)
#pragma unroll
        for (int j = 0; j < NF; ++j) acc[i][j] = (f32x4)(0.f);

    for (int k0 = 0; k0 < K; k0 += BK) {
        // --- stage all tiles direct-to-LDS (tasks round-robin over 8 waves) ---
#pragma unroll
        for (int tau = wid; tau < NT; tau += 8) {
            const u16* g;
            u16* l;
            if (tau < AT) {
                g = Ahg + (size_t)(row0 + tau * 16 + lrow) * K + k0 + lch;
                l = &Ah[tau * 16][0];
            } else if (HAS_AL && tau < 2 * AT) {
                g = Alg + (size_t)(row0 + (tau - AT) * 16 + lrow) * K + k0 + lch;
                l = &Al[(tau - AT) * 16][0];
            } else if (tau < NA + BT) {
                int tb = tau - NA;
                g = Whg + (size_t)(tb * 16 + lrow) * K + k0 + lch;
                l = &Bh[tb * 16][0];
            } else {
                int tb = tau - NA - BT;
                g = Wlg + (size_t)(tb * 16 + lrow) * K + k0 + lch;
                l = &Bl[tb * 16][0];
            }
            gload_lds16(g, l);
        }
        __syncthreads();   // drains vmcnt (global_load_lds) before fragment reads

        bf16x8 ah[MF], al[MF], bh[NF], bl[NF];
#pragma unroll
        for (int mf = 0; mf < MF; ++mf) {
            ah[mf] = *(const bf16x8*)&Ah[wm + mf * 16 + lr][lk];
            if constexpr (HAS_AL)
                al[mf] = *(const bf16x8*)&Al[wm + mf * 16 + lr][lk];
        }
#pragma unroll
        for (int nf = 0; nf < NF; ++nf) {
            bh[nf] = *(const bf16x8*)&Bh[wn + nf * 16 + lr][lk];
            bl[nf] = *(const bf16x8*)&Bl[wn + nf * 16 + lr][lk];
        }
#pragma unroll
        for (int mf = 0; mf < MF; ++mf)
#pragma unroll
            for (int nf = 0; nf < NF; ++nf) {
                acc[mf][nf] = __builtin_amdgcn_mfma_f32_16x16x32_bf16(ah[mf], bh[nf], acc[mf][nf], 0, 0, 0);
                acc[mf][nf] = __builtin_amdgcn_mfma_f32_16x16x32_bf16(ah[mf], bl[nf], acc[mf][nf], 0, 0, 0);
                if constexpr (HAS_AL)
                    acc[mf][nf] = __builtin_amdgcn_mfma_f32_16x16x32_bf16(al[mf], bh[nf], acc[mf][nf], 0, 0, 0);
            }
        __syncthreads();
    }

#pragma unroll
    for (int mf = 0; mf < MF; ++mf) {
#pragma unroll
        for (int r = 0; r < 4; ++r) {
            int grow = row0 + wm + mf * 16 + (lane >> 4) * 4 + r;
            if (grow < M) {
                float dv = dinv[grow];
#pragma unroll
                for (int nf = 0; nf < NF; ++nf)
                    h_out[(size_t)grow * NOUT + wn + nf * 16 + lr] = f2bf(acc[mf][nf][r] * dv);
            }
        }
    }
}

__launch_bounds__(512, 8)
__global__ void k_gemm1(const u16* __restrict__ Xh, const u16* __restrict__ Xl,
                        const u16* __restrict__ Wh, const u16* __restrict__ Wl,
                        const float* __restrict__ dinv, u16* __restrict__ h_out, int M) {
    gemm_body<IN_CH, HID, true>(blockIdx.x, Xh, Xl, Wh, Wl, dinv, h_out, M);
}

__launch_bounds__(512, 8)
__global__ void k_gemm2(const u16* __restrict__ A,
                        const u16* __restrict__ Wh, const u16* __restrict__ Wl,
                        const float* __restrict__ dinv, u16* __restrict__ h_out, int M) {
    gemm_body<HID, LAT, false>(blockIdx.x, A, nullptr, Wh, Wl, dinv, h_out, M);
}

// ---------------- aggregates (node-major bf16 h, 16 B/lane gathers, 8-deep MLP) ----------------

__device__ inline void acc8(float* a, uint4 v) {
    a[0] += __uint_as_float(v.x << 16);
    a[1] += __uint_as_float(v.x & 0xFFFF0000u);
    a[2] += __uint_as_float(v.y << 16);
    a[3] += __uint_as_float(v.y & 0xFFFF0000u);
    a[4] += __uint_as_float(v.z << 16);
    a[5] += __uint_as_float(v.z & 0xFFFF0000u);
    a[6] += __uint_as_float(v.w << 16);
    a[7] += __uint_as_float(v.w & 0xFFFF0000u);
}

// OUT_BF16: store 8 bf16 (16 B) per thread (out feeds gemm2); else f32 pair of 16 B.
template<int C, bool RELU, bool OUT_BF16>
__global__ void k_aggregate(const int* __restrict__ row_ptr,
                            const int* __restrict__ row_end,
                            const int* __restrict__ csr,
                            const u16* __restrict__ h,
                            const float* __restrict__ dinv,
                            const float* __restrict__ bias,
                            void* __restrict__ out_v, int n) {
    constexpr int QSHIFT = (C == 128) ? 4 : 3;     // C/8 threads per node
    long long tid = (long long)blockIdx.x * blockDim.x + threadIdx.x;
    int node = (int)(tid >> QSHIFT);
    if (node >= n) return;
    int c = ((int)tid & ((1 << QSHIFT) - 1)) * 8;

    int k   = row_ptr[node];
    int end = row_end[node];

    float a[8] = {0.f, 0.f, 0.f, 0.f, 0.f, 0.f, 0.f, 0.f};
    acc8(a, *(const uint4*)&h[(size_t)node * C + c]);    // self-loop term

    for (; k + 8 <= end; k += 8) {                        // 8 gathers in flight
        int s0 = csr[k],     s1 = csr[k + 1], s2 = csr[k + 2], s3 = csr[k + 3];
        int s4 = csr[k + 4], s5 = csr[k + 5], s6 = csr[k + 6], s7 = csr[k + 7];
        uint4 v0 = *(const uint4*)&h[(size_t)s0 * C + c];
        uint4 v1 = *(const uint4*)&h[(size_t)s1 * C + c];
        uint4 v2 = *(const uint4*)&h[(size_t)s2 * C + c];
        uint4 v3 = *(const uint4*)&h[(size_t)s3 * C + c];
        uint4 v4 = *(const uint4*)&h[(size_t)s4 * C + c];
        uint4 v5 = *(const uint4*)&h[(size_t)s5 * C + c];
        uint4 v6 = *(const uint4*)&h[(size_t)s6 * C + c];
        uint4 v7 = *(const uint4*)&h[(size_t)s7 * C + c];
        acc8(a, v0); acc8(a, v1); acc8(a, v2); acc8(a, v3);
        acc8(a, v4); acc8(a, v5); acc8(a, v6); acc8(a, v7);
    }
    if (k + 4 <= end) {
        int s0 = csr[k], s1 = csr[k + 1], s2 = csr[k + 2], s3 = csr[k + 3];
        uint4 v0 = *(const uint4*)&h[(size_t)s0 * C + c];
        uint4 v1 = *(const uint4*)&h[(size_t)s1 * C + c];
        uint4 v2 = *(const uint4*)&h[(size_t)s2 * C + c];
        uint4 v3 = *(const uint4*)&h[(size_t)s3 * C + c];
        acc8(a, v0); acc8(a, v1); acc8(a, v2); acc8(a, v3);
        k += 4;
    }
    for (; k < end; ++k) {
        int s0 = csr[k];
        acc8(a, *(const uint4*)&h[(size_t)s0 * C + c]);
    }

    float dvn = dinv[node];
    float4 b0 = *(const float4*)&bias[c];
    float4 b1 = *(const float4*)&bias[c + 4];
    float o[8];
    o[0] = fmaf(a[0], dvn, b0.x);
    o[1] = fmaf(a[1], dvn, b0.y);
    o[2] = fmaf(a[2], dvn, b0.z);
    o[3] = fmaf(a[3], dvn, b0.w);
    o[4] = fmaf(a[4], dvn, b1.x);
    o[5] = fmaf(a[5], dvn, b1.y);
    o[6] = fmaf(a[6], dvn, b1.z);
    o[7] = fmaf(a[7], dvn, b1.w);
    if (RELU) {
#pragma unroll
        for (int j = 0; j < 8; ++j) o[j] = fmaxf(o[j], 0.f);
    }
    if (OUT_BF16) {
        u16 r[8];
#pragma unroll
        for (int j = 0; j < 8; ++j) r[j] = f2bf(o[j]);
        *(uint4*)&((u16*)out_v)[(size_t)node * C + c] = *(const uint4*)r;
    } else {
        float* out = (float*)out_v;
        *(f32x4*)&out[(size_t)node * C + c]     = *(const f32x4*)&o[0];
        *(f32x4*)&out[(size_t)node * C + c + 4] = *(const f32x4*)&o[4];
    }
}

// ---------------- launch ----------------

extern "C" void kernel_launch(void* const* d_in, const int* in_sizes, int n_in,
                              void* d_out, int out_size, void* d_ws, size_t ws_size,
                              hipStream_t stream) {
    const float* x   = (const float*)d_in[0];
    const int*   ei  = (const int*)d_in[1];     // harness delivers integers as int32
    const float* W1  = (const float*)d_in[2];
    const float* b1  = (const float*)d_in[3];
    const float* W2  = (const float*)d_in[4];
    const float* b2  = (const float*)d_in[5];
    float*       out = (float*)d_out;

    const int N = in_sizes[0] / IN_CH;
    const int E = in_sizes[1] / 2;
    const int* esrc = ei;
    const int* edst = ei + E;

    const int NSB = (N + SBN - 1) / SBN;   // super-buckets (98)
    const int NBB = (E + EPB - 1) / EPB;   // bin blocks (196)
    const int GB  = (N + 63) / 64;         // gemm blocks (BM=64)

    char* ws = (char*)d_ws;
    int*   sb_fill = (int*)ws;    ws += (size_t)((NSB + 31) & ~31) * 4;
    u32*   sbe     = (u32*)ws;    ws += (size_t)NSB * SB_CAP * 4;   // SB-grouped edges
    int*   csr     = (int*)ws;    ws += (size_t)NSB * SB_CAP * 4;   // slotted CSR
    int*   row_ptr = (int*)ws;    ws += (size_t)N * 4;
    int*   row_end = (int*)ws;    ws += (size_t)N * 4;
    float* dinv    = (float*)ws;  ws += (size_t)N * 4;
    // NOTE: gemm tail-blocks stream up to 16KB past each A/W table (OOB rows are
    // masked in the epilogue) — every gemm input below is followed by more ws.
    u16*   Xh      = (u16*)ws;    ws += (size_t)N * IN_CH * 2;  // x hi (bf16)
    u16*   Xl      = (u16*)ws;    ws += (size_t)N * IN_CH * 2;  // x lo (bf16)
    u16*   W1h     = (u16*)ws;    ws += (size_t)HID * IN_CH * 2;
    u16*   W1l     = (u16*)ws;    ws += (size_t)HID * IN_CH * 2;
    u16*   W2h     = (u16*)ws;    ws += (size_t)LAT * HID * 2;
    u16*   W2l     = (u16*)ws;    ws += (size_t)LAT * HID * 2;
    u16*   h1      = (u16*)ws;    ws += (size_t)N * HID * 2;   // bf16, dinv folded
    u16*   out1    = (u16*)ws;    ws += (size_t)N * HID * 2;   // agg1 out (bf16, GEMM2's A)
    u16*   h2      = (u16*)ws;    ws += (size_t)N * LAT * 2;   // bf16, dinv folded (last: not a gemm input)

    dim3 blk(256);

    // ---- prep ----
    k_zero   <<<1, 128, 0, stream>>>(sb_fill, NSB);
    k_split_w<<<(HID * IN_CH + 255) / 256, blk, 0, stream>>>(W1, W1h, W1l, HID * IN_CH);
    k_split_w<<<(LAT * HID + 255) / 256, blk, 0, stream>>>(W2, W2h, W2l, LAT * HID);

    // ---- coalesced-write CSR build + fused x split ----
    k_bin_sb<<<NBB, dim3(512), 0, stream>>>(esrc, edst, sb_fill, sbe, x, Xh, Xl, E, NSB, N);
    k_sbsort<<<NSB * 2, dim3(512), 0, stream>>>(sb_fill, sbe, csr, row_ptr, row_end, dinv, N);

    // ---- layer 1: 256 -> 128, relu ----
    k_gemm1<<<GB, dim3(512), 0, stream>>>(Xh, Xl, W1h, W1l, dinv, h1, N);
    {
        long long tot = (long long)N * 16;
        k_aggregate<HID, true, true><<<(unsigned)((tot + 255) / 256), blk, 0, stream>>>(
            row_ptr, row_end, csr, h1, dinv, b1, out1, N);
    }

    // ---- layer 2: 128 -> 64 ----
    k_gemm2<<<GB, dim3(512), 0, stream>>>(out1, W2h, W2l, dinv, h2, N);
    {
        long long tot = (long long)N * 8;
        k_aggregate<LAT, false, false><<<(unsigned)((tot + 255) / 256), blk, 0, stream>>>(
            row_ptr, row_end, csr, h2, dinv, b2, out, N);
    }
}

// Round 20
// 193.291 us; speedup vs baseline: 1.2291x; 1.2291x over previous
//
#include <hip/hip_runtime.h>
#include <math.h>

constexpr int IN_CH = 256;
constexpr int HID   = 128;
constexpr int LAT   = 64;

constexpr int SBN    = 1024;    // nodes per super-bucket
constexpr int SB_CAP = 18432;   // edges per SB region: mean 16384, +16 sigma
constexpr int EPB    = 8192;    // edges per bin block
constexpr int HCAP   = 9472;    // per-half-SB LDS staging: mean 8192, +14 sigma

typedef unsigned short u16;
typedef unsigned int   u32;
typedef unsigned char  u8;
typedef __bf16  bf16x8 __attribute__((ext_vector_type(8)));
typedef float   f32x4  __attribute__((ext_vector_type(4)));

__device__ inline u16 f2bf(float f) {
    unsigned u = __float_as_uint(f);
    unsigned r = u + 0x7FFF + ((u >> 16) & 1);
    return (u16)(r >> 16);
}
__device__ inline float bf2f(u16 h) {
    return __uint_as_float((unsigned)h << 16);
}

// direct global->LDS 16B copy; lds base must be wave-uniform (HW: dst = base + lane*16)
__device__ inline void gload_lds16(const u16* g, u16* lds) {
    __builtin_amdgcn_global_load_lds(
        (const __attribute__((address_space(1))) void*)g,
        (__attribute__((address_space(3))) void*)lds,
        16, 0, 0);
}

// ---------------- merged prep: zero sb_fill + split W1, W2 ----------------

__global__ void k_prep(const float* __restrict__ W1, u16* __restrict__ W1h, u16* __restrict__ W1l,
                       const float* __restrict__ W2, u16* __restrict__ W2h, u16* __restrict__ W2l,
                       int* __restrict__ sb_fill, int nsb) {
    int i = blockIdx.x * blockDim.x + threadIdx.x;
    if (i < nsb) sb_fill[i] = 0;
    if (i < HID * IN_CH) {
        float v = W1[i];
        u16 h = f2bf(v);
        W1h[i] = h;
        W1l[i] = f2bf(v - bf2f(h));
    }
    if (i < LAT * HID) {
        float v = W2[i];
        u16 h = f2bf(v);
        W2h[i] = h;
        W2l[i] = f2bf(v - bf2f(h));
    }
}

// ---------------- coalesced-write CSR build ----------------

// stage 1: per-block LDS counting sort by super-bucket, then COALESCED run flush.
__launch_bounds__(512)
__global__ void k_bin_sb(const int* __restrict__ esrc, const int* __restrict__ edst,
                         int* __restrict__ sb_fill, u32* __restrict__ sbe,
                         int E, int NSB) {
    __shared__ u32 sorted[EPB];      // 32 KB
    __shared__ u8  ssb[EPB];         // 8 KB
    __shared__ int cnt[128], sc[128], excl[128], fil[128], off[128];

    const int t  = threadIdx.x;
    const int e0 = blockIdx.x * EPB;

    for (int j = t; j < 128; j += 512) { cnt[j] = 0; fil[j] = 0; }
    __syncthreads();

#pragma unroll
    for (int it = 0; it < EPB / 512; ++it) {
        int e = e0 + it * 512 + t;
        if (e < E) atomicAdd(&cnt[edst[e] >> 10], 1);
    }
    __syncthreads();

    if (t < 128) sc[t] = cnt[t];
    __syncthreads();
#pragma unroll
    for (int o = 1; o < 128; o <<= 1) {
        int u = 0;
        if (t < 128 && t >= o) u = sc[t - o];
        __syncthreads();
        if (t < 128) sc[t] += u;
        __syncthreads();
    }
    if (t < 128) excl[t] = sc[t] - cnt[t];
    if (t < NSB) off[t] = atomicAdd(&sb_fill[t], cnt[t]);
    __syncthreads();

#pragma unroll
    for (int it = 0; it < EPB / 512; ++it) {
        int e = e0 + it * 512 + t;
        if (e < E) {
            int d  = edst[e];
            int sb = d >> 10;
            int pos = excl[sb] + atomicAdd(&fil[sb], 1);
            sorted[pos] = (u32)esrc[e] | ((u32)(d & 1023) << 17);
            ssb[pos]    = (u8)sb;
        }
    }
    __syncthreads();

    int mtot = sc[127];
    for (int i = t; i < mtot; i += 512) {
        int sb = ssb[i];
        int o  = off[sb] + (i - excl[sb]);
        if (o < SB_CAP) sbe[(size_t)sb * SB_CAP + o] = sorted[i];
    }
}

// stage 2: per-half-SB counting sort; streamed passes, LDS staging, coalesced flush.
__launch_bounds__(512)
__global__ void k_sbsort(const int* __restrict__ sb_fill, const u32* __restrict__ sbe,
                         int* __restrict__ csr, int* __restrict__ row_ptr,
                         int* __restrict__ row_end, float* __restrict__ dinv, int N) {
    __shared__ int cnt[SBN];
    __shared__ int exclh[512];
    __shared__ int fillb[512];
    __shared__ int lsrc[HCAP];
    __shared__ int wsum[8];
    __shared__ int sh_h1base, sh_mtot;

    const int t    = threadIdx.x;
    const int sb   = blockIdx.x >> 1;
    const int half = blockIdx.x & 1;
    const int m    = min(sb_fill[sb], SB_CAP);
    const size_t base = (size_t)sb * SB_CAP;
    const int node0 = sb * SBN;

    for (int j = t; j < SBN; j += 512) cnt[j] = 0;
    fillb[t & 511] = 0;
    __syncthreads();

    for (int i = t; i < m; i += 512)
        atomicAdd(&cnt[sbe[base + i] >> 17], 1);
    __syncthreads();

    int c0 = cnt[2 * t], c1 = cnt[2 * t + 1];
    int p  = c0 + c1;
    int lane = t & 63, wid = t >> 6;
    int v = p;
#pragma unroll
    for (int o = 1; o < 64; o <<= 1) {
        int u = __shfl_up(v, o, 64);
        if (lane >= o) v += u;
    }
    if (lane == 63) wsum[wid] = v;
    __syncthreads();
    int woff = 0;
#pragma unroll
    for (int w = 0; w < 8; ++w) if (w < wid) woff += wsum[w];
    int incl = woff + v;
    int eP   = incl - p;
    if (t == 511) sh_mtot = incl;
    if (t == 256) sh_h1base = eP;

#pragma unroll
    for (int q = 0; q < 2; ++q) {
        int j  = 2 * t + q;
        int ex = q ? (eP + c0) : eP;
        int cc = q ? c1 : c0;
        if ((j >> 9) == half) {
            exclh[j & 511] = ex;
            int node = node0 + j;
            if (node < N) {
                row_ptr[node] = (int)base + ex;
                row_end[node] = (int)base + ex + cc;
                dinv[node]    = rsqrtf((float)(cc + 1));   // +1 self-loop
            }
        }
    }
    __syncthreads();

    const int hb = (half == 0) ? 0 : sh_h1base;
    int mh = (half == 0) ? sh_h1base : (sh_mtot - sh_h1base);

    for (int i = t; i < m; i += 512) {
        u32 p2  = sbe[base + i];
        int d10 = p2 >> 17;
        if ((d10 >> 9) == half) {
            int slot = atomicAdd(&fillb[d10 & 511], 1);
            int pos  = exclh[d10 & 511] - hb + slot;
            if (pos < HCAP) lsrc[pos] = (int)(p2 & 0x1FFFF);
        }
    }
    __syncthreads();

    if (mh > HCAP) mh = HCAP;
    for (int i = t; i < mh; i += 512) csr[base + hb + i] = lsrc[i];
}

// ---------------- gemm1: r13 form — inline f32->hi/lo split, BM=64, x3 MFMA ----------------
// h = bf16( (A @ W^T) * dinv[row] ), node-major.

__launch_bounds__(512, 4)
__global__ void k_gemm1(const float* __restrict__ A,
                        const u16* __restrict__ Wh, const u16* __restrict__ Wl,
                        const float* __restrict__ dinv, u16* __restrict__ h_out, int M) {
    constexpr int K = IN_CH, NOUT = HID;
    constexpr int BM = 64, BK = 32, LDT = 40, THREADS = 512;
    constexpr int WAVES_N = 4, WM = 32, WN = 32, MF = 2, NF = 2;

    __shared__ u16 Ah[BM][LDT], Al[BM][LDT];
    __shared__ u16 Bh[NOUT][LDT], Bl[NOUT][LDT];

    const int t    = threadIdx.x;
    const int lane = t & 63;
    const int wid  = t >> 6;
    const int wm   = (wid / WAVES_N) * WM;
    const int wn   = (wid % WAVES_N) * WN;
    const int lr   = lane & 15;
    const int lk   = (lane >> 4) * 8;
    const int row0 = blockIdx.x * BM;

    f32x4 acc[MF][NF];
#pragma unroll
    for (int i = 0; i < MF; ++i)
#pragma unroll
        for (int j = 0; j < NF; ++j) acc[i][j] = (f32x4)(0.f);

    for (int k0 = 0; k0 < K; k0 += BK) {
        {   // stage A tile (BM x BK f32), hi/lo split: 512 quads, 1 per thread
            int r  = t >> 3;
            int c4 = (t & 7) * 4;
            int gr = row0 + r;
            float4 v = make_float4(0.f, 0.f, 0.f, 0.f);
            if (gr < M) v = *(const float4*)&A[(size_t)gr * K + k0 + c4];
            ushort4 hi, lo;
            hi.x = f2bf(v.x); lo.x = f2bf(v.x - bf2f(hi.x));
            hi.y = f2bf(v.y); lo.y = f2bf(v.y - bf2f(hi.y));
            hi.z = f2bf(v.z); lo.z = f2bf(v.z - bf2f(hi.z));
            hi.w = f2bf(v.w); lo.w = f2bf(v.w - bf2f(hi.w));
            *(ushort4*)&Ah[r][c4] = hi;
            *(ushort4*)&Al[r][c4] = lo;
        }
#pragma unroll
        for (int it = 0; it < 2; ++it) {   // stage W tiles (NOUT*BK/4/THREADS = 2)
            int q  = it * THREADS + t;
            int r  = q >> 3;
            int c4 = (q & 7) * 4;
            *(ushort4*)&Bh[r][c4] = *(const ushort4*)&Wh[(size_t)r * K + k0 + c4];
            *(ushort4*)&Bl[r][c4] = *(const ushort4*)&Wl[(size_t)r * K + k0 + c4];
        }
        __syncthreads();

        bf16x8 ah[MF], al[MF], bh[NF], bl[NF];
#pragma unroll
        for (int mf = 0; mf < MF; ++mf) {
            ah[mf] = *(const bf16x8*)&Ah[wm + mf * 16 + lr][lk];
            al[mf] = *(const bf16x8*)&Al[wm + mf * 16 + lr][lk];
        }
#pragma unroll
        for (int nf = 0; nf < NF; ++nf) {
            bh[nf] = *(const bf16x8*)&Bh[wn + nf * 16 + lr][lk];
            bl[nf] = *(const bf16x8*)&Bl[wn + nf * 16 + lr][lk];
        }
#pragma unroll
        for (int mf = 0; mf < MF; ++mf)
#pragma unroll
            for (int nf = 0; nf < NF; ++nf) {
                acc[mf][nf] = __builtin_amdgcn_mfma_f32_16x16x32_bf16(ah[mf], bh[nf], acc[mf][nf], 0, 0, 0);
                acc[mf][nf] = __builtin_amdgcn_mfma_f32_16x16x32_bf16(ah[mf], bl[nf], acc[mf][nf], 0, 0, 0);
                acc[mf][nf] = __builtin_amdgcn_mfma_f32_16x16x32_bf16(al[mf], bh[nf], acc[mf][nf], 0, 0, 0);
            }
        __syncthreads();
    }

#pragma unroll
    for (int mf = 0; mf < MF; ++mf) {
#pragma unroll
        for (int r = 0; r < 4; ++r) {
            int grow = row0 + wm + mf * 16 + (lane >> 4) * 4 + r;
            if (grow < M) {
                float dv = dinv[grow];
#pragma unroll
                for (int nf = 0; nf < NF; ++nf)
                    h_out[(size_t)grow * NOUT + wn + nf * 16 + lr] = f2bf(acc[mf][nf][r] * dv);
            }
        }
    }
}

// ---------------- gemm2: global_load_lds staging (A bf16, no split pass needed) ----------------

__launch_bounds__(512, 8)
__global__ void k_gemm2(const u16* __restrict__ Ag,
                        const u16* __restrict__ Whg, const u16* __restrict__ Wlg,
                        const float* __restrict__ dinv, u16* __restrict__ h_out, int M) {
    constexpr int K = HID, NOUT = LAT;
    constexpr int BM = 64, BK = 32;
    constexpr int WAVES_N = 2, WM = 16, WN = 32, MF = 1, NF = 2;
    constexpr int AT = BM / 16;        // 4 A tasks
    constexpr int BT = NOUT / 16;      // 4 W tasks per array
    constexpr int NT = AT + 2 * BT;    // 12 tasks

    __shared__ u16 Ah[BM][BK];
    __shared__ u16 Bh[NOUT][BK], Bl[NOUT][BK];

    const int t    = threadIdx.x;
    const int lane = t & 63;
    const int wid  = t >> 6;
    const int wm   = (wid / WAVES_N) * WM;
    const int wn   = (wid % WAVES_N) * WN;
    const int lr   = lane & 15;
    const int lk   = (lane >> 4) * 8;
    const int row0 = blockIdx.x * BM;

    const int lrow = lane >> 2;
    const int lch  = (lane & 3) * 8;

    f32x4 acc[MF][NF];
#pragma unroll
    for (int i = 0; i < MF; ++i)
#pragma unroll
        for (int j = 0; j < NF; ++j) acc[i][j] = (f32x4)(0.f);

    for (int k0 = 0; k0 < K; k0 += BK) {
        for (int tau = wid; tau < NT; tau += 8) {
            const u16* g;
            u16* l;
            if (tau < AT) {
                g = Ag + (size_t)(row0 + tau * 16 + lrow) * K + k0 + lch;
                l = &Ah[tau * 16][0];
            } else if (tau < AT + BT) {
                int tb = tau - AT;
                g = Whg + (size_t)(tb * 16 + lrow) * K + k0 + lch;
                l = &Bh[tb * 16][0];
            } else {
                int tb = tau - AT - BT;
                g = Wlg + (size_t)(tb * 16 + lrow) * K + k0 + lch;
                l = &Bl[tb * 16][0];
            }
            gload_lds16(g, l);
        }
        __syncthreads();

        bf16x8 ah[MF], bh[NF], bl[NF];
#pragma unroll
        for (int mf = 0; mf < MF; ++mf)
            ah[mf] = *(const bf16x8*)&Ah[wm + mf * 16 + lr][lk];
#pragma unroll
        for (int nf = 0; nf < NF; ++nf) {
            bh[nf] = *(const bf16x8*)&Bh[wn + nf * 16 + lr][lk];
            bl[nf] = *(const bf16x8*)&Bl[wn + nf * 16 + lr][lk];
        }
#pragma unroll
        for (int mf = 0; mf < MF; ++mf)
#pragma unroll
            for (int nf = 0; nf < NF; ++nf) {
                acc[mf][nf] = __builtin_amdgcn_mfma_f32_16x16x32_bf16(ah[mf], bh[nf], acc[mf][nf], 0, 0, 0);
                acc[mf][nf] = __builtin_amdgcn_mfma_f32_16x16x32_bf16(ah[mf], bl[nf], acc[mf][nf], 0, 0, 0);
            }
        __syncthreads();
    }

#pragma unroll
    for (int mf = 0; mf < MF; ++mf) {
#pragma unroll
        for (int r = 0; r < 4; ++r) {
            int grow = row0 + wm + mf * 16 + (lane >> 4) * 4 + r;
            if (grow < M) {
                float dv = dinv[grow];
#pragma unroll
                for (int nf = 0; nf < NF; ++nf)
                    h_out[(size_t)grow * NOUT + wn + nf * 16 + lr] = f2bf(acc[mf][nf][r] * dv);
            }
        }
    }
}

// ---------------- aggregates (node-major bf16 h, 16 B/lane gathers, 8-deep MLP) ----------------

__device__ inline void acc8(float* a, uint4 v) {
    a[0] += __uint_as_float(v.x << 16);
    a[1] += __uint_as_float(v.x & 0xFFFF0000u);
    a[2] += __uint_as_float(v.y << 16);
    a[3] += __uint_as_float(v.y & 0xFFFF0000u);
    a[4] += __uint_as_float(v.z << 16);
    a[5] += __uint_as_float(v.z & 0xFFFF0000u);
    a[6] += __uint_as_float(v.w << 16);
    a[7] += __uint_as_float(v.w & 0xFFFF0000u);
}

// OUT_BF16: store 8 bf16 (16 B) per thread (out feeds gemm2); else f32 pair of 16 B.
template<int C, bool RELU, bool OUT_BF16>
__global__ void k_aggregate(const int* __restrict__ row_ptr,
                            const int* __restrict__ row_end,
                            const int* __restrict__ csr,
                            const u16* __restrict__ h,
                            const float* __restrict__ dinv,
                            const float* __restrict__ bias,
                            void* __restrict__ out_v, int n) {
    constexpr int QSHIFT = (C == 128) ? 4 : 3;     // C/8 threads per node
    long long tid = (long long)blockIdx.x * blockDim.x + threadIdx.x;
    int node = (int)(tid >> QSHIFT);
    if (node >= n) return;
    int c = ((int)tid & ((1 << QSHIFT) - 1)) * 8;

    int k   = row_ptr[node];
    int end = row_end[node];

    float a[8] = {0.f, 0.f, 0.f, 0.f, 0.f, 0.f, 0.f, 0.f};
    acc8(a, *(const uint4*)&h[(size_t)node * C + c]);    // self-loop term

    for (; k + 8 <= end; k += 8) {                        // 8 gathers in flight
        int s0 = csr[k],     s1 = csr[k + 1], s2 = csr[k + 2], s3 = csr[k + 3];
        int s4 = csr[k + 4], s5 = csr[k + 5], s6 = csr[k + 6], s7 = csr[k + 7];
        uint4 v0 = *(const uint4*)&h[(size_t)s0 * C + c];
        uint4 v1 = *(const uint4*)&h[(size_t)s1 * C + c];
        uint4 v2 = *(const uint4*)&h[(size_t)s2 * C + c];
        uint4 v3 = *(const uint4*)&h[(size_t)s3 * C + c];
        uint4 v4 = *(const uint4*)&h[(size_t)s4 * C + c];
        uint4 v5 = *(const uint4*)&h[(size_t)s5 * C + c];
        uint4 v6 = *(const uint4*)&h[(size_t)s6 * C + c];
        uint4 v7 = *(const uint4*)&h[(size_t)s7 * C + c];
        acc8(a, v0); acc8(a, v1); acc8(a, v2); acc8(a, v3);
        acc8(a, v4); acc8(a, v5); acc8(a, v6); acc8(a, v7);
    }
    if (k + 4 <= end) {
        int s0 = csr[k], s1 = csr[k + 1], s2 = csr[k + 2], s3 = csr[k + 3];
        uint4 v0 = *(const uint4*)&h[(size_t)s0 * C + c];
        uint4 v1 = *(const uint4*)&h[(size_t)s1 * C + c];
        uint4 v2 = *(const uint4*)&h[(size_t)s2 * C + c];
        uint4 v3 = *(const uint4*)&h[(size_t)s3 * C + c];
        acc8(a, v0); acc8(a, v1); acc8(a, v2); acc8(a, v3);
        k += 4;
    }
    for (; k < end; ++k) {
        int s0 = csr[k];
        acc8(a, *(const uint4*)&h[(size_t)s0 * C + c]);
    }

    float dvn = dinv[node];
    float4 b0 = *(const float4*)&bias[c];
    float4 b1 = *(const float4*)&bias[c + 4];
    float o[8];
    o[0] = fmaf(a[0], dvn, b0.x);
    o[1] = fmaf(a[1], dvn, b0.y);
    o[2] = fmaf(a[2], dvn, b0.z);
    o[3] = fmaf(a[3], dvn, b0.w);
    o[4] = fmaf(a[4], dvn, b1.x);
    o[5] = fmaf(a[5], dvn, b1.y);
    o[6] = fmaf(a[6], dvn, b1.z);
    o[7] = fmaf(a[7], dvn, b1.w);
    if (RELU) {
#pragma unroll
        for (int j = 0; j < 8; ++j) o[j] = fmaxf(o[j], 0.f);
    }
    if (OUT_BF16) {
        u16 r[8];
#pragma unroll
        for (int j = 0; j < 8; ++j) r[j] = f2bf(o[j]);
        *(uint4*)&((u16*)out_v)[(size_t)node * C + c] = *(const uint4*)r;
    } else {
        float* out = (float*)out_v;
        *(f32x4*)&out[(size_t)node * C + c]     = *(const f32x4*)&o[0];
        *(f32x4*)&out[(size_t)node * C + c + 4] = *(const f32x4*)&o[4];
    }
}

// ---------------- launch ----------------

extern "C" void kernel_launch(void* const* d_in, const int* in_sizes, int n_in,
                              void* d_out, int out_size, void* d_ws, size_t ws_size,
                              hipStream_t stream) {
    const float* x   = (const float*)d_in[0];
    const int*   ei  = (const int*)d_in[1];     // harness delivers integers as int32
    const float* W1  = (const float*)d_in[2];
    const float* b1  = (const float*)d_in[3];
    const float* W2  = (const float*)d_in[4];
    const float* b2  = (const float*)d_in[5];
    float*       out = (float*)d_out;

    const int N = in_sizes[0] / IN_CH;
    const int E = in_sizes[1] / 2;
    const int* esrc = ei;
    const int* edst = ei + E;

    const int NSB = (N + SBN - 1) / SBN;   // super-buckets (98)
    const int NBB = (E + EPB - 1) / EPB;   // bin blocks (196)
    const int GB  = (N + 63) / 64;         // gemm blocks (BM=64)

    char* ws = (char*)d_ws;
    int*   sb_fill = (int*)ws;    ws += (size_t)((NSB + 31) & ~31) * 4;
    u32*   sbe     = (u32*)ws;    ws += (size_t)NSB * SB_CAP * 4;   // SB-grouped edges
    int*   csr     = (int*)ws;    ws += (size_t)NSB * SB_CAP * 4;   // slotted CSR
    int*   row_ptr = (int*)ws;    ws += (size_t)N * 4;
    int*   row_end = (int*)ws;    ws += (size_t)N * 4;
    float* dinv    = (float*)ws;  ws += (size_t)N * 4;
    // NOTE: k_gemm2's tail-block gload streams up to ~16KB past out1/W2 tables
    // (OOB rows masked in epilogue) — keep each followed by more ws.
    u16*   W1h     = (u16*)ws;    ws += (size_t)HID * IN_CH * 2;
    u16*   W1l     = (u16*)ws;    ws += (size_t)HID * IN_CH * 2;
    u16*   W2h     = (u16*)ws;    ws += (size_t)LAT * HID * 2;
    u16*   W2l     = (u16*)ws;    ws += (size_t)LAT * HID * 2;
    u16*   h1      = (u16*)ws;    ws += (size_t)N * HID * 2;   // bf16, dinv folded
    u16*   out1    = (u16*)ws;    ws += (size_t)N * HID * 2;   // agg1 out (bf16, GEMM2's A)
    u16*   h2      = (u16*)ws;    ws += (size_t)N * LAT * 2;   // bf16, dinv folded (last)

    dim3 blk(256);

    // ---- prep (merged zero + W splits) ----
    k_prep<<<(HID * IN_CH + 255) / 256, blk, 0, stream>>>(W1, W1h, W1l, W2, W2h, W2l,
                                                          sb_fill, NSB);

    // ---- coalesced-write CSR build ----
    k_bin_sb<<<NBB, dim3(512), 0, stream>>>(esrc, edst, sb_fill, sbe, E, NSB);
    k_sbsort<<<NSB * 2, dim3(512), 0, stream>>>(sb_fill, sbe, csr, row_ptr, row_end, dinv, N);

    // ---- layer 1: 256 -> 128, relu ----
    k_gemm1<<<GB, dim3(512), 0, stream>>>(x, W1h, W1l, dinv, h1, N);
    {
        long long tot = (long long)N * 16;
        k_aggregate<HID, true, true><<<(unsigned)((tot + 255) / 256), blk, 0, stream>>>(
            row_ptr, row_end, csr, h1, dinv, b1, out1, N);
    }

    // ---- layer 2: 128 -> 64 ----
    k_gemm2<<<GB, dim3(512), 0, stream>>>(out1, W2h, W2l, dinv, h2, N);
    {
        long long tot = (long long)N * 8;
        k_aggregate<LAT, false, false><<<(unsigned)((tot + 255) / 256), blk, 0, stream>>>(
            row_ptr, row_end, csr, h2, dinv, b2, out, N);
    }
}

// Round 21
// 192.405 us; speedup vs baseline: 1.2347x; 1.0046x over previous
//
#include <hip/hip_runtime.h>
#include <math.h>

constexpr int IN_CH = 256;
constexpr int HID   = 128;
constexpr int LAT   = 64;

constexpr int SBN    = 1024;    // nodes per super-bucket
constexpr int SB_CAP = 18432;   // edges per SB region: mean 16384, +16 sigma
constexpr int EPB    = 8192;    // edges per bin block
constexpr int HCAP   = 9472;    // per-half-SB LDS staging: mean 8192, +14 sigma

typedef unsigned short u16;
typedef unsigned int   u32;
typedef unsigned char  u8;
typedef __bf16  bf16x8 __attribute__((ext_vector_type(8)));
typedef float   f32x4  __attribute__((ext_vector_type(4)));

__device__ inline u16 f2bf(float f) {
    unsigned u = __float_as_uint(f);
    unsigned r = u + 0x7FFF + ((u >> 16) & 1);
    return (u16)(r >> 16);
}
__device__ inline float bf2f(u16 h) {
    return __uint_as_float((unsigned)h << 16);
}

// direct global->LDS 16B copy; lds base must be wave-uniform (HW: dst = base + lane*16)
__device__ inline void gload_lds16(const u16* g, u16* lds) {
    __builtin_amdgcn_global_load_lds(
        (const __attribute__((address_space(1))) void*)g,
        (__attribute__((address_space(3))) void*)lds,
        16, 0, 0);
}

// ---------------- merged prep: zero sb_fill + split W1, W2 ----------------

__global__ void k_prep(const float* __restrict__ W1, u16* __restrict__ W1h, u16* __restrict__ W1l,
                       const float* __restrict__ W2, u16* __restrict__ W2h, u16* __restrict__ W2l,
                       int* __restrict__ sb_fill, int nsb) {
    int i = blockIdx.x * blockDim.x + threadIdx.x;
    if (i < nsb) sb_fill[i] = 0;
    if (i < HID * IN_CH) {
        float v = W1[i];
        u16 h = f2bf(v);
        W1h[i] = h;
        W1l[i] = f2bf(v - bf2f(h));
    }
    if (i < LAT * HID) {
        float v = W2[i];
        u16 h = f2bf(v);
        W2h[i] = h;
        W2l[i] = f2bf(v - bf2f(h));
    }
}

// ---------------- coalesced-write CSR build ----------------

// stage 1: per-block LDS counting sort by super-bucket, then COALESCED run flush.
__launch_bounds__(512)
__global__ void k_bin_sb(const int* __restrict__ esrc, const int* __restrict__ edst,
                         int* __restrict__ sb_fill, u32* __restrict__ sbe,
                         int E, int NSB) {
    __shared__ u32 sorted[EPB];      // 32 KB
    __shared__ u8  ssb[EPB];         // 8 KB
    __shared__ int cnt[128], sc[128], excl[128], fil[128], off[128];

    const int t  = threadIdx.x;
    const int e0 = blockIdx.x * EPB;

    for (int j = t; j < 128; j += 512) { cnt[j] = 0; fil[j] = 0; }
    __syncthreads();

#pragma unroll
    for (int it = 0; it < EPB / 512; ++it) {
        int e = e0 + it * 512 + t;
        if (e < E) atomicAdd(&cnt[edst[e] >> 10], 1);
    }
    __syncthreads();

    if (t < 128) sc[t] = cnt[t];
    __syncthreads();
#pragma unroll
    for (int o = 1; o < 128; o <<= 1) {
        int u = 0;
        if (t < 128 && t >= o) u = sc[t - o];
        __syncthreads();
        if (t < 128) sc[t] += u;
        __syncthreads();
    }
    if (t < 128) excl[t] = sc[t] - cnt[t];
    if (t < NSB) off[t] = atomicAdd(&sb_fill[t], cnt[t]);
    __syncthreads();

#pragma unroll
    for (int it = 0; it < EPB / 512; ++it) {
        int e = e0 + it * 512 + t;
        if (e < E) {
            int d  = edst[e];
            int sb = d >> 10;
            int pos = excl[sb] + atomicAdd(&fil[sb], 1);
            sorted[pos] = (u32)esrc[e] | ((u32)(d & 1023) << 17);
            ssb[pos]    = (u8)sb;
        }
    }
    __syncthreads();

    int mtot = sc[127];
    for (int i = t; i < mtot; i += 512) {
        int sb = ssb[i];
        int o  = off[sb] + (i - excl[sb]);
        if (o < SB_CAP) sbe[(size_t)sb * SB_CAP + o] = sorted[i];
    }
}

// stage 2: per-half-SB counting sort; streamed passes, LDS staging, coalesced flush.
__launch_bounds__(512)
__global__ void k_sbsort(const int* __restrict__ sb_fill, const u32* __restrict__ sbe,
                         int* __restrict__ csr, int* __restrict__ row_ptr,
                         int* __restrict__ row_end, float* __restrict__ dinv, int N) {
    __shared__ int cnt[SBN];
    __shared__ int exclh[512];
    __shared__ int fillb[512];
    __shared__ int lsrc[HCAP];
    __shared__ int wsum[8];
    __shared__ int sh_h1base, sh_mtot;

    const int t    = threadIdx.x;
    const int sb   = blockIdx.x >> 1;
    const int half = blockIdx.x & 1;
    const int m    = min(sb_fill[sb], SB_CAP);
    const size_t base = (size_t)sb * SB_CAP;
    const int node0 = sb * SBN;

    for (int j = t; j < SBN; j += 512) cnt[j] = 0;
    fillb[t & 511] = 0;
    __syncthreads();

    for (int i = t; i < m; i += 512)
        atomicAdd(&cnt[sbe[base + i] >> 17], 1);
    __syncthreads();

    int c0 = cnt[2 * t], c1 = cnt[2 * t + 1];
    int p  = c0 + c1;
    int lane = t & 63, wid = t >> 6;
    int v = p;
#pragma unroll
    for (int o = 1; o < 64; o <<= 1) {
        int u = __shfl_up(v, o, 64);
        if (lane >= o) v += u;
    }
    if (lane == 63) wsum[wid] = v;
    __syncthreads();
    int woff = 0;
#pragma unroll
    for (int w = 0; w < 8; ++w) if (w < wid) woff += wsum[w];
    int incl = woff + v;
    int eP   = incl - p;
    if (t == 511) sh_mtot = incl;
    if (t == 256) sh_h1base = eP;

#pragma unroll
    for (int q = 0; q < 2; ++q) {
        int j  = 2 * t + q;
        int ex = q ? (eP + c0) : eP;
        int cc = q ? c1 : c0;
        if ((j >> 9) == half) {
            exclh[j & 511] = ex;
            int node = node0 + j;
            if (node < N) {
                row_ptr[node] = (int)base + ex;
                row_end[node] = (int)base + ex + cc;
                dinv[node]    = rsqrtf((float)(cc + 1));   // +1 self-loop
            }
        }
    }
    __syncthreads();

    const int hb = (half == 0) ? 0 : sh_h1base;
    int mh = (half == 0) ? sh_h1base : (sh_mtot - sh_h1base);

    for (int i = t; i < m; i += 512) {
        u32 p2  = sbe[base + i];
        int d10 = p2 >> 17;
        if ((d10 >> 9) == half) {
            int slot = atomicAdd(&fillb[d10 & 511], 1);
            int pos  = exclh[d10 & 511] - hb + slot;
            if (pos < HCAP) lsrc[pos] = (int)(p2 & 0x1FFFF);
        }
    }
    __syncthreads();

    if (mh > HCAP) mh = HCAP;
    for (int i = t; i < mh; i += 512) csr[base + hb + i] = lsrc[i];
}

// ---------------- gemm1: hybrid — inline f32 A split (ds_write) + gload_lds W staging ----
// h = bf16( (A @ W^T) * dinv[row] ), node-major. BM=64, x3 MFMA.

__launch_bounds__(512, 4)
__global__ void k_gemm1(const float* __restrict__ A,
                        const u16* __restrict__ Wh, const u16* __restrict__ Wl,
                        const float* __restrict__ dinv, u16* __restrict__ h_out, int M) {
    constexpr int K = IN_CH, NOUT = HID;
    constexpr int BM = 64, BK = 32, LDT = 40;
    constexpr int WAVES_N = 4, WM = 32, WN = 32, MF = 2, NF = 2;
    constexpr int BT = NOUT / 16;      // 8 W tasks per array, 16 total over 8 waves

    __shared__ u16 Ah[BM][LDT], Al[BM][LDT];     // padded (2-way free reads)
    __shared__ u16 Bh[NOUT][BK], Bl[NOUT][BK];   // linear 64B rows (gload dest)

    const int t    = threadIdx.x;
    const int lane = t & 63;
    const int wid  = t >> 6;
    const int wm   = (wid / WAVES_N) * WM;
    const int wn   = (wid % WAVES_N) * WN;
    const int lr   = lane & 15;
    const int lk   = (lane >> 4) * 8;
    const int row0 = blockIdx.x * BM;

    const int lrow = lane >> 2;        // gload task: row within 16-row group
    const int lch  = (lane & 3) * 8;   // elem offset within a 64B row

    f32x4 acc[MF][NF];
#pragma unroll
    for (int i = 0; i < MF; ++i)
#pragma unroll
        for (int j = 0; j < NF; ++j) acc[i][j] = (f32x4)(0.f);

    for (int k0 = 0; k0 < K; k0 += BK) {
        // --- W tiles direct-to-LDS: 2 gload instr/wave (16 tasks / 8 waves) ---
#pragma unroll
        for (int tau = wid; tau < 2 * BT; tau += 8) {
            const u16* g;
            u16* l;
            if (tau < BT) {
                g = Wh + (size_t)(tau * 16 + lrow) * K + k0 + lch;
                l = &Bh[tau * 16][0];
            } else {
                int tb = tau - BT;
                g = Wl + (size_t)(tb * 16 + lrow) * K + k0 + lch;
                l = &Bl[tb * 16][0];
            }
            gload_lds16(g, l);
        }
        // --- A tile (BM x BK f32), inline hi/lo split: 1 quad/thread ---
        {
            int r  = t >> 3;
            int c4 = (t & 7) * 4;
            int gr = row0 + r;
            float4 v = make_float4(0.f, 0.f, 0.f, 0.f);
            if (gr < M) v = *(const float4*)&A[(size_t)gr * K + k0 + c4];
            ushort4 hi, lo;
            hi.x = f2bf(v.x); lo.x = f2bf(v.x - bf2f(hi.x));
            hi.y = f2bf(v.y); lo.y = f2bf(v.y - bf2f(hi.y));
            hi.z = f2bf(v.z); lo.z = f2bf(v.z - bf2f(hi.z));
            hi.w = f2bf(v.w); lo.w = f2bf(v.w - bf2f(hi.w));
            *(ushort4*)&Ah[r][c4] = hi;
            *(ushort4*)&Al[r][c4] = lo;
        }
        __syncthreads();   // drains ds_writes (lgkmcnt) AND gload (vmcnt)

        bf16x8 ah[MF], al[MF], bh[NF], bl[NF];
#pragma unroll
        for (int mf = 0; mf < MF; ++mf) {
            ah[mf] = *(const bf16x8*)&Ah[wm + mf * 16 + lr][lk];
            al[mf] = *(const bf16x8*)&Al[wm + mf * 16 + lr][lk];
        }
#pragma unroll
        for (int nf = 0; nf < NF; ++nf) {
            bh[nf] = *(const bf16x8*)&Bh[wn + nf * 16 + lr][lk];
            bl[nf] = *(const bf16x8*)&Bl[wn + nf * 16 + lr][lk];
        }
#pragma unroll
        for (int mf = 0; mf < MF; ++mf)
#pragma unroll
            for (int nf = 0; nf < NF; ++nf) {
                acc[mf][nf] = __builtin_amdgcn_mfma_f32_16x16x32_bf16(ah[mf], bh[nf], acc[mf][nf], 0, 0, 0);
                acc[mf][nf] = __builtin_amdgcn_mfma_f32_16x16x32_bf16(ah[mf], bl[nf], acc[mf][nf], 0, 0, 0);
                acc[mf][nf] = __builtin_amdgcn_mfma_f32_16x16x32_bf16(al[mf], bh[nf], acc[mf][nf], 0, 0, 0);
            }
        __syncthreads();
    }

#pragma unroll
    for (int mf = 0; mf < MF; ++mf) {
#pragma unroll
        for (int r = 0; r < 4; ++r) {
            int grow = row0 + wm + mf * 16 + (lane >> 4) * 4 + r;
            if (grow < M) {
                float dv = dinv[grow];
#pragma unroll
                for (int nf = 0; nf < NF; ++nf)
                    h_out[(size_t)grow * NOUT + wn + nf * 16 + lr] = f2bf(acc[mf][nf][r] * dv);
            }
        }
    }
}

// ---------------- gemm2: global_load_lds staging (A bf16, no split pass needed) ----------------

__launch_bounds__(512, 8)
__global__ void k_gemm2(const u16* __restrict__ Ag,
                        const u16* __restrict__ Whg, const u16* __restrict__ Wlg,
                        const float* __restrict__ dinv, u16* __restrict__ h_out, int M) {
    constexpr int K = HID, NOUT = LAT;
    constexpr int BM = 64, BK = 32;
    constexpr int WAVES_N = 2, WM = 16, WN = 32, MF = 1, NF = 2;
    constexpr int AT = BM / 16;        // 4 A tasks
    constexpr int BT = NOUT / 16;      // 4 W tasks per array
    constexpr int NT = AT + 2 * BT;    // 12 tasks

    __shared__ u16 Ah[BM][BK];
    __shared__ u16 Bh[NOUT][BK], Bl[NOUT][BK];

    const int t    = threadIdx.x;
    const int lane = t & 63;
    const int wid  = t >> 6;
    const int wm   = (wid / WAVES_N) * WM;
    const int wn   = (wid % WAVES_N) * WN;
    const int lr   = lane & 15;
    const int lk   = (lane >> 4) * 8;
    const int row0 = blockIdx.x * BM;

    const int lrow = lane >> 2;
    const int lch  = (lane & 3) * 8;

    f32x4 acc[MF][NF];
#pragma unroll
    for (int i = 0; i < MF; ++i)
#pragma unroll
        for (int j = 0; j < NF; ++j) acc[i][j] = (f32x4)(0.f);

    for (int k0 = 0; k0 < K; k0 += BK) {
        for (int tau = wid; tau < NT; tau += 8) {
            const u16* g;
            u16* l;
            if (tau < AT) {
                g = Ag + (size_t)(row0 + tau * 16 + lrow) * K + k0 + lch;
                l = &Ah[tau * 16][0];
            } else if (tau < AT + BT) {
                int tb = tau - AT;
                g = Whg + (size_t)(tb * 16 + lrow) * K + k0 + lch;
                l = &Bh[tb * 16][0];
            } else {
                int tb = tau - AT - BT;
                g = Wlg + (size_t)(tb * 16 + lrow) * K + k0 + lch;
                l = &Bl[tb * 16][0];
            }
            gload_lds16(g, l);
        }
        __syncthreads();

        bf16x8 ah[MF], bh[NF], bl[NF];
#pragma unroll
        for (int mf = 0; mf < MF; ++mf)
            ah[mf] = *(const bf16x8*)&Ah[wm + mf * 16 + lr][lk];
#pragma unroll
        for (int nf = 0; nf < NF; ++nf) {
            bh[nf] = *(const bf16x8*)&Bh[wn + nf * 16 + lr][lk];
            bl[nf] = *(const bf16x8*)&Bl[wn + nf * 16 + lr][lk];
        }
#pragma unroll
        for (int mf = 0; mf < MF; ++mf)
#pragma unroll
            for (int nf = 0; nf < NF; ++nf) {
                acc[mf][nf] = __builtin_amdgcn_mfma_f32_16x16x32_bf16(ah[mf], bh[nf], acc[mf][nf], 0, 0, 0);
                acc[mf][nf] = __builtin_amdgcn_mfma_f32_16x16x32_bf16(ah[mf], bl[nf], acc[mf][nf], 0, 0, 0);
            }
        __syncthreads();
    }

#pragma unroll
    for (int mf = 0; mf < MF; ++mf) {
#pragma unroll
        for (int r = 0; r < 4; ++r) {
            int grow = row0 + wm + mf * 16 + (lane >> 4) * 4 + r;
            if (grow < M) {
                float dv = dinv[grow];
#pragma unroll
                for (int nf = 0; nf < NF; ++nf)
                    h_out[(size_t)grow * NOUT + wn + nf * 16 + lr] = f2bf(acc[mf][nf][r] * dv);
            }
        }
    }
}

// ---------------- aggregates (node-major bf16 h, 16 B/lane gathers, 8-deep MLP) ----------------

__device__ inline void acc8(float* a, uint4 v) {
    a[0] += __uint_as_float(v.x << 16);
    a[1] += __uint_as_float(v.x & 0xFFFF0000u);
    a[2] += __uint_as_float(v.y << 16);
    a[3] += __uint_as_float(v.y & 0xFFFF0000u);
    a[4] += __uint_as_float(v.z << 16);
    a[5] += __uint_as_float(v.z & 0xFFFF0000u);
    a[6] += __uint_as_float(v.w << 16);
    a[7] += __uint_as_float(v.w & 0xFFFF0000u);
}

// OUT_BF16: store 8 bf16 (16 B) per thread (out feeds gemm2); else f32 pair of 16 B.
template<int C, bool RELU, bool OUT_BF16>
__global__ void k_aggregate(const int* __restrict__ row_ptr,
                            const int* __restrict__ row_end,
                            const int* __restrict__ csr,
                            const u16* __restrict__ h,
                            const float* __restrict__ dinv,
                            const float* __restrict__ bias,
                            void* __restrict__ out_v, int n) {
    constexpr int QSHIFT = (C == 128) ? 4 : 3;     // C/8 threads per node
    long long tid = (long long)blockIdx.x * blockDim.x + threadIdx.x;
    int node = (int)(tid >> QSHIFT);
    if (node >= n) return;
    int c = ((int)tid & ((1 << QSHIFT) - 1)) * 8;

    int k   = row_ptr[node];
    int end = row_end[node];

    float a[8] = {0.f, 0.f, 0.f, 0.f, 0.f, 0.f, 0.f, 0.f};
    acc8(a, *(const uint4*)&h[(size_t)node * C + c]);    // self-loop term

    for (; k + 8 <= end; k += 8) {                        // 8 gathers in flight
        int s0 = csr[k],     s1 = csr[k + 1], s2 = csr[k + 2], s3 = csr[k + 3];
        int s4 = csr[k + 4], s5 = csr[k + 5], s6 = csr[k + 6], s7 = csr[k + 7];
        uint4 v0 = *(const uint4*)&h[(size_t)s0 * C + c];
        uint4 v1 = *(const uint4*)&h[(size_t)s1 * C + c];
        uint4 v2 = *(const uint4*)&h[(size_t)s2 * C + c];
        uint4 v3 = *(const uint4*)&h[(size_t)s3 * C + c];
        uint4 v4 = *(const uint4*)&h[(size_t)s4 * C + c];
        uint4 v5 = *(const uint4*)&h[(size_t)s5 * C + c];
        uint4 v6 = *(const uint4*)&h[(size_t)s6 * C + c];
        uint4 v7 = *(const uint4*)&h[(size_t)s7 * C + c];
        acc8(a, v0); acc8(a, v1); acc8(a, v2); acc8(a, v3);
        acc8(a, v4); acc8(a, v5); acc8(a, v6); acc8(a, v7);
    }
    if (k + 4 <= end) {
        int s0 = csr[k], s1 = csr[k + 1], s2 = csr[k + 2], s3 = csr[k + 3];
        uint4 v0 = *(const uint4*)&h[(size_t)s0 * C + c];
        uint4 v1 = *(const uint4*)&h[(size_t)s1 * C + c];
        uint4 v2 = *(const uint4*)&h[(size_t)s2 * C + c];
        uint4 v3 = *(const uint4*)&h[(size_t)s3 * C + c];
        acc8(a, v0); acc8(a, v1); acc8(a, v2); acc8(a, v3);
        k += 4;
    }
    for (; k < end; ++k) {
        int s0 = csr[k];
        acc8(a, *(const uint4*)&h[(size_t)s0 * C + c]);
    }

    float dvn = dinv[node];
    float4 b0 = *(const float4*)&bias[c];
    float4 b1 = *(const float4*)&bias[c + 4];
    float o[8];
    o[0] = fmaf(a[0], dvn, b0.x);
    o[1] = fmaf(a[1], dvn, b0.y);
    o[2] = fmaf(a[2], dvn, b0.z);
    o[3] = fmaf(a[3], dvn, b0.w);
    o[4] = fmaf(a[4], dvn, b1.x);
    o[5] = fmaf(a[5], dvn, b1.y);
    o[6] = fmaf(a[6], dvn, b1.z);
    o[7] = fmaf(a[7], dvn, b1.w);
    if (RELU) {
#pragma unroll
        for (int j = 0; j < 8; ++j) o[j] = fmaxf(o[j], 0.f);
    }
    if (OUT_BF16) {
        u16 r[8];
#pragma unroll
        for (int j = 0; j < 8; ++j) r[j] = f2bf(o[j]);
        *(uint4*)&((u16*)out_v)[(size_t)node * C + c] = *(const uint4*)r;
    } else {
        float* out = (float*)out_v;
        *(f32x4*)&out[(size_t)node * C + c]     = *(const f32x4*)&o[0];
        *(f32x4*)&out[(size_t)node * C + c + 4] = *(const f32x4*)&o[4];
    }
}

// ---------------- launch ----------------

extern "C" void kernel_launch(void* const* d_in, const int* in_sizes, int n_in,
                              void* d_out, int out_size, void* d_ws, size_t ws_size,
                              hipStream_t stream) {
    const float* x   = (const float*)d_in[0];
    const int*   ei  = (const int*)d_in[1];     // harness delivers integers as int32
    const float* W1  = (const float*)d_in[2];
    const float* b1  = (const float*)d_in[3];
    const float* W2  = (const float*)d_in[4];
    const float* b2  = (const float*)d_in[5];
    float*       out = (float*)d_out;

    const int N = in_sizes[0] / IN_CH;
    const int E = in_sizes[1] / 2;
    const int* esrc = ei;
    const int* edst = ei + E;

    const int NSB = (N + SBN - 1) / SBN;   // super-buckets (98)
    const int NBB = (E + EPB - 1) / EPB;   // bin blocks (196)
    const int GB  = (N + 63) / 64;         // gemm blocks (BM=64)

    char* ws = (char*)d_ws;
    int*   sb_fill = (int*)ws;    ws += (size_t)((NSB + 31) & ~31) * 4;
    u32*   sbe     = (u32*)ws;    ws += (size_t)NSB * SB_CAP * 4;   // SB-grouped edges
    int*   csr     = (int*)ws;    ws += (size_t)NSB * SB_CAP * 4;   // slotted CSR
    int*   row_ptr = (int*)ws;    ws += (size_t)N * 4;
    int*   row_end = (int*)ws;    ws += (size_t)N * 4;
    float* dinv    = (float*)ws;  ws += (size_t)N * 4;
    // NOTE: k_gemm2's tail-block gload streams up to ~16KB past out1/W2 tables
    // (OOB rows masked in epilogue) — keep each followed by more ws.
    u16*   W1h     = (u16*)ws;    ws += (size_t)HID * IN_CH * 2;
    u16*   W1l     = (u16*)ws;    ws += (size_t)HID * IN_CH * 2;
    u16*   W2h     = (u16*)ws;    ws += (size_t)LAT * HID * 2;
    u16*   W2l     = (u16*)ws;    ws += (size_t)LAT * HID * 2;
    u16*   h1      = (u16*)ws;    ws += (size_t)N * HID * 2;   // bf16, dinv folded
    u16*   out1    = (u16*)ws;    ws += (size_t)N * HID * 2;   // agg1 out (bf16, GEMM2's A)
    u16*   h2      = (u16*)ws;    ws += (size_t)N * LAT * 2;   // bf16, dinv folded (last)

    dim3 blk(256);

    // ---- prep (merged zero + W splits) ----
    k_prep<<<(HID * IN_CH + 255) / 256, blk, 0, stream>>>(W1, W1h, W1l, W2, W2h, W2l,
                                                          sb_fill, NSB);

    // ---- coalesced-write CSR build ----
    k_bin_sb<<<NBB, dim3(512), 0, stream>>>(esrc, edst, sb_fill, sbe, E, NSB);
    k_sbsort<<<NSB * 2, dim3(512), 0, stream>>>(sb_fill, sbe, csr, row_ptr, row_end, dinv, N);

    // ---- layer 1: 256 -> 128, relu ----
    k_gemm1<<<GB, dim3(512), 0, stream>>>(x, W1h, W1l, dinv, h1, N);
    {
        long long tot = (long long)N * 16;
        k_aggregate<HID, true, true><<<(unsigned)((tot + 255) / 256), blk, 0, stream>>>(
            row_ptr, row_end, csr, h1, dinv, b1, out1, N);
    }

    // ---- layer 2: 128 -> 64 ----
    k_gemm2<<<GB, dim3(512), 0, stream>>>(out1, W2h, W2l, dinv, h2, N);
    {
        long long tot = (long long)N * 8;
        k_aggregate<LAT, false, false><<<(unsigned)((tot + 255) / 256), blk, 0, stream>>>(
            row_ptr, row_end, csr, h2, dinv, b2, out, N);
    }
}

// Round 22
// 190.058 us; speedup vs baseline: 1.2500x; 1.0123x over previous
//
#include <hip/hip_runtime.h>
#include <math.h>

constexpr int IN_CH = 256;
constexpr int HID   = 128;
constexpr int LAT   = 64;

constexpr int SBN    = 1024;    // nodes per super-bucket
constexpr int SB_CAP = 19456;   // edges per SB region: padded mean 17920, +11 sigma
constexpr int EPB    = 8192;    // edges per bin block
constexpr int HCAP   = 9984;    // per-half-SB LDS staging: padded mean 8960, +10 sigma

typedef unsigned short u16;
typedef unsigned int   u32;
typedef unsigned char  u8;
typedef __bf16  bf16x8 __attribute__((ext_vector_type(8)));
typedef float   f32x4  __attribute__((ext_vector_type(4)));

__device__ inline u16 f2bf(float f) {
    unsigned u = __float_as_uint(f);
    unsigned r = u + 0x7FFF + ((u >> 16) & 1);
    return (u16)(r >> 16);
}
__device__ inline float bf2f(u16 h) {
    return __uint_as_float((unsigned)h << 16);
}

// direct global->LDS 16B copy; lds base must be wave-uniform (HW: dst = base + lane*16)
__device__ inline void gload_lds16(const u16* g, u16* lds) {
    __builtin_amdgcn_global_load_lds(
        (const __attribute__((address_space(1))) void*)g,
        (__attribute__((address_space(3))) void*)lds,
        16, 0, 0);
}

// ---------------- merged prep: zero sb_fill + split W1, W2 + zero sentinel rows ----------------

__global__ void k_prep(const float* __restrict__ W1, u16* __restrict__ W1h, u16* __restrict__ W1l,
                       const float* __restrict__ W2, u16* __restrict__ W2h, u16* __restrict__ W2l,
                       int* __restrict__ sb_fill, int nsb,
                       u16* __restrict__ h1z, u16* __restrict__ h2z) {
    int i = blockIdx.x * blockDim.x + threadIdx.x;
    if (i < nsb) sb_fill[i] = 0;
    if (i < HID * IN_CH) {
        float v = W1[i];
        u16 h = f2bf(v);
        W1h[i] = h;
        W1l[i] = f2bf(v - bf2f(h));
    }
    if (i < LAT * HID) {
        float v = W2[i];
        u16 h = f2bf(v);
        W2h[i] = h;
        W2l[i] = f2bf(v - bf2f(h));
    }
    // zero the sentinel rows (gather target of pad edges)
    if (i < HID) h1z[i] = 0;
    if (i < LAT) h2z[i] = 0;
}

// ---------------- coalesced-write CSR build ----------------

// stage 1: per-block LDS counting sort by super-bucket, then COALESCED run flush.
__launch_bounds__(512)
__global__ void k_bin_sb(const int* __restrict__ esrc, const int* __restrict__ edst,
                         int* __restrict__ sb_fill, u32* __restrict__ sbe,
                         int E, int NSB) {
    __shared__ u32 sorted[EPB];      // 32 KB
    __shared__ u8  ssb[EPB];         // 8 KB
    __shared__ int cnt[128], sc[128], excl[128], fil[128], off[128];

    const int t  = threadIdx.x;
    const int e0 = blockIdx.x * EPB;

    for (int j = t; j < 128; j += 512) { cnt[j] = 0; fil[j] = 0; }
    __syncthreads();

#pragma unroll
    for (int it = 0; it < EPB / 512; ++it) {
        int e = e0 + it * 512 + t;
        if (e < E) atomicAdd(&cnt[edst[e] >> 10], 1);
    }
    __syncthreads();

    if (t < 128) sc[t] = cnt[t];
    __syncthreads();
#pragma unroll
    for (int o = 1; o < 128; o <<= 1) {
        int u = 0;
        if (t < 128 && t >= o) u = sc[t - o];
        __syncthreads();
        if (t < 128) sc[t] += u;
        __syncthreads();
    }
    if (t < 128) excl[t] = sc[t] - cnt[t];
    if (t < NSB) off[t] = atomicAdd(&sb_fill[t], cnt[t]);
    __syncthreads();

#pragma unroll
    for (int it = 0; it < EPB / 512; ++it) {
        int e = e0 + it * 512 + t;
        if (e < E) {
            int d  = edst[e];
            int sb = d >> 10;
            int pos = excl[sb] + atomicAdd(&fil[sb], 1);
            sorted[pos] = (u32)esrc[e] | ((u32)(d & 1023) << 17);
            ssb[pos]    = (u8)sb;
        }
    }
    __syncthreads();

    int mtot = sc[127];
    for (int i = t; i < mtot; i += 512) {
        int sb = ssb[i];
        int o  = off[sb] + (i - excl[sb]);
        if (o < SB_CAP) sbe[(size_t)sb * SB_CAP + o] = sorted[i];
    }
}

// stage 2: per-half-SB counting sort with PADDED rows (each node's run padded to x4
// with sentinel src = N -> zero row). Streamed passes, LDS staging, coalesced flush.
__launch_bounds__(512)
__global__ void k_sbsort(const int* __restrict__ sb_fill, const u32* __restrict__ sbe,
                         int* __restrict__ csr, int* __restrict__ row_ptr,
                         int* __restrict__ row_end, float* __restrict__ dinv, int N) {
    __shared__ int cnt[SBN];
    __shared__ int exclh[512];       // PADDED exclusive offsets for my half's nodes
    __shared__ int fillb[512];
    __shared__ int lsrc[HCAP];
    __shared__ int wsum[8];
    __shared__ int sh_h1base, sh_mtot;

    const int t    = threadIdx.x;
    const int sb   = blockIdx.x >> 1;
    const int half = blockIdx.x & 1;
    const int m    = min(sb_fill[sb], SB_CAP);
    const size_t base = (size_t)sb * SB_CAP;
    const int node0 = sb * SBN;

    for (int j = t; j < SBN; j += 512) cnt[j] = 0;
    fillb[t & 511] = 0;
    __syncthreads();

    for (int i = t; i < m; i += 512)
        atomicAdd(&cnt[sbe[base + i] >> 17], 1);
    __syncthreads();

    // scan PADDED counts: pc = (c+3)&~3
    int c0 = cnt[2 * t], c1 = cnt[2 * t + 1];
    int pc0 = (c0 + 3) & ~3, pc1 = (c1 + 3) & ~3;
    int p  = pc0 + pc1;
    int lane = t & 63, wid = t >> 6;
    int v = p;
#pragma unroll
    for (int o = 1; o < 64; o <<= 1) {
        int u = __shfl_up(v, o, 64);
        if (lane >= o) v += u;
    }
    if (lane == 63) wsum[wid] = v;
    __syncthreads();
    int woff = 0;
#pragma unroll
    for (int w = 0; w < 8; ++w) if (w < wid) woff += wsum[w];
    int incl = woff + v;          // inclusive padded total over pairs
    int eP   = incl - p;          // exclusive padded offset
    if (t == 511) sh_mtot = incl;
    if (t == 256) sh_h1base = eP;

#pragma unroll
    for (int q = 0; q < 2; ++q) {
        int j  = 2 * t + q;
        int ex = q ? (eP + pc0) : eP;
        int cc = q ? c1 : c0;
        int pc = q ? pc1 : pc0;
        if ((j >> 9) == half) {
            exclh[j & 511] = ex;
            int node = node0 + j;
            if (node < N) {
                row_ptr[node] = (int)base + ex;
                row_end[node] = (int)base + ex + pc;            // PADDED end
                dinv[node]    = rsqrtf((float)(cc + 1));        // actual count +1 self-loop
            }
        }
    }
    __syncthreads();

    const int hb = (half == 0) ? 0 : sh_h1base;
    int mh = (half == 0) ? sh_h1base : (sh_mtot - sh_h1base);   // padded half size

    // scatter actual edges into padded slots
    for (int i = t; i < m; i += 512) {
        u32 p2  = sbe[base + i];
        int d10 = p2 >> 17;
        if ((d10 >> 9) == half) {
            int slot = atomicAdd(&fillb[d10 & 511], 1);
            int pos  = exclh[d10 & 511] - hb + slot;
            if (pos < HCAP) lsrc[pos] = (int)(p2 & 0x1FFFF);
        }
    }
    __syncthreads();

    // fill pad slots with sentinel N (gathers the zero row; exact 0 contribution)
#pragma unroll
    for (int q = 0; q < 2; ++q) {
        int j = 2 * t + q;
        if ((j >> 9) == half) {
            int cc = cnt[j];
            int pc = (cc + 3) & ~3;
            int ex = exclh[j & 511] - hb;
            for (int i = cc; i < pc; ++i)
                if (ex + i < HCAP) lsrc[ex + i] = N;
        }
    }
    __syncthreads();

    if (mh > HCAP) mh = HCAP;
    for (int i = t; i < mh; i += 512) csr[base + hb + i] = lsrc[i];
}

// ---------------- gemm1: r13/r20 form — inline f32->hi/lo split, BM=64, x3 MFMA ----------------
// h = bf16( (A @ W^T) * dinv[row] ), node-major.

__launch_bounds__(512, 4)
__global__ void k_gemm1(const float* __restrict__ A,
                        const u16* __restrict__ Wh, const u16* __restrict__ Wl,
                        const float* __restrict__ dinv, u16* __restrict__ h_out, int M) {
    constexpr int K = IN_CH, NOUT = HID;
    constexpr int BM = 64, BK = 32, LDT = 40, THREADS = 512;
    constexpr int WAVES_N = 4, WM = 32, WN = 32, MF = 2, NF = 2;

    __shared__ u16 Ah[BM][LDT], Al[BM][LDT];
    __shared__ u16 Bh[NOUT][LDT], Bl[NOUT][LDT];

    const int t    = threadIdx.x;
    const int lane = t & 63;
    const int wid  = t >> 6;
    const int wm   = (wid / WAVES_N) * WM;
    const int wn   = (wid % WAVES_N) * WN;
    const int lr   = lane & 15;
    const int lk   = (lane >> 4) * 8;
    const int row0 = blockIdx.x * BM;

    f32x4 acc[MF][NF];
#pragma unroll
    for (int i = 0; i < MF; ++i)
#pragma unroll
        for (int j = 0; j < NF; ++j) acc[i][j] = (f32x4)(0.f);

    for (int k0 = 0; k0 < K; k0 += BK) {
        {   // stage A tile (BM x BK f32), hi/lo split: 1 quad per thread
            int r  = t >> 3;
            int c4 = (t & 7) * 4;
            int gr = row0 + r;
            float4 v = make_float4(0.f, 0.f, 0.f, 0.f);
            if (gr < M) v = *(const float4*)&A[(size_t)gr * K + k0 + c4];
            ushort4 hi, lo;
            hi.x = f2bf(v.x); lo.x = f2bf(v.x - bf2f(hi.x));
            hi.y = f2bf(v.y); lo.y = f2bf(v.y - bf2f(hi.y));
            hi.z = f2bf(v.z); lo.z = f2bf(v.z - bf2f(hi.z));
            hi.w = f2bf(v.w); lo.w = f2bf(v.w - bf2f(hi.w));
            *(ushort4*)&Ah[r][c4] = hi;
            *(ushort4*)&Al[r][c4] = lo;
        }
#pragma unroll
        for (int it = 0; it < 2; ++it) {   // stage W tiles
            int q  = it * THREADS + t;
            int r  = q >> 3;
            int c4 = (q & 7) * 4;
            *(ushort4*)&Bh[r][c4] = *(const ushort4*)&Wh[(size_t)r * K + k0 + c4];
            *(ushort4*)&Bl[r][c4] = *(const ushort4*)&Wl[(size_t)r * K + k0 + c4];
        }
        __syncthreads();

        bf16x8 ah[MF], al[MF], bh[NF], bl[NF];
#pragma unroll
        for (int mf = 0; mf < MF; ++mf) {
            ah[mf] = *(const bf16x8*)&Ah[wm + mf * 16 + lr][lk];
            al[mf] = *(const bf16x8*)&Al[wm + mf * 16 + lr][lk];
        }
#pragma unroll
        for (int nf = 0; nf < NF; ++nf) {
            bh[nf] = *(const bf16x8*)&Bh[wn + nf * 16 + lr][lk];
            bl[nf] = *(const bf16x8*)&Bl[wn + nf * 16 + lr][lk];
        }
#pragma unroll
        for (int mf = 0; mf < MF; ++mf)
#pragma unroll
            for (int nf = 0; nf < NF; ++nf) {
                acc[mf][nf] = __builtin_amdgcn_mfma_f32_16x16x32_bf16(ah[mf], bh[nf], acc[mf][nf], 0, 0, 0);
                acc[mf][nf] = __builtin_amdgcn_mfma_f32_16x16x32_bf16(ah[mf], bl[nf], acc[mf][nf], 0, 0, 0);
                acc[mf][nf] = __builtin_amdgcn_mfma_f32_16x16x32_bf16(al[mf], bh[nf], acc[mf][nf], 0, 0, 0);
            }
        __syncthreads();
    }

#pragma unroll
    for (int mf = 0; mf < MF; ++mf) {
#pragma unroll
        for (int r = 0; r < 4; ++r) {
            int grow = row0 + wm + mf * 16 + (lane >> 4) * 4 + r;
            if (grow < M) {
                float dv = dinv[grow];
#pragma unroll
                for (int nf = 0; nf < NF; ++nf)
                    h_out[(size_t)grow * NOUT + wn + nf * 16 + lr] = f2bf(acc[mf][nf][r] * dv);
            }
        }
    }
}

// ---------------- gemm2: global_load_lds staging (A bf16, no split pass needed) ----------------

__launch_bounds__(512, 8)
__global__ void k_gemm2(const u16* __restrict__ Ag,
                        const u16* __restrict__ Whg, const u16* __restrict__ Wlg,
                        const float* __restrict__ dinv, u16* __restrict__ h_out, int M) {
    constexpr int K = HID, NOUT = LAT;
    constexpr int BM = 64, BK = 32;
    constexpr int WAVES_N = 2, WM = 16, WN = 32, MF = 1, NF = 2;
    constexpr int AT = BM / 16;        // 4 A tasks
    constexpr int BT = NOUT / 16;      // 4 W tasks per array
    constexpr int NT = AT + 2 * BT;    // 12 tasks

    __shared__ u16 Ah[BM][BK];
    __shared__ u16 Bh[NOUT][BK], Bl[NOUT][BK];

    const int t    = threadIdx.x;
    const int lane = t & 63;
    const int wid  = t >> 6;
    const int wm   = (wid / WAVES_N) * WM;
    const int wn   = (wid % WAVES_N) * WN;
    const int lr   = lane & 15;
    const int lk   = (lane >> 4) * 8;
    const int row0 = blockIdx.x * BM;

    const int lrow = lane >> 2;
    const int lch  = (lane & 3) * 8;

    f32x4 acc[MF][NF];
#pragma unroll
    for (int i = 0; i < MF; ++i)
#pragma unroll
        for (int j = 0; j < NF; ++j) acc[i][j] = (f32x4)(0.f);

    for (int k0 = 0; k0 < K; k0 += BK) {
        for (int tau = wid; tau < NT; tau += 8) {
            const u16* g;
            u16* l;
            if (tau < AT) {
                g = Ag + (size_t)(row0 + tau * 16 + lrow) * K + k0 + lch;
                l = &Ah[tau * 16][0];
            } else if (tau < AT + BT) {
                int tb = tau - AT;
                g = Whg + (size_t)(tb * 16 + lrow) * K + k0 + lch;
                l = &Bh[tb * 16][0];
            } else {
                int tb = tau - AT - BT;
                g = Wlg + (size_t)(tb * 16 + lrow) * K + k0 + lch;
                l = &Bl[tb * 16][0];
            }
            gload_lds16(g, l);
        }
        __syncthreads();

        bf16x8 ah[MF], bh[NF], bl[NF];
#pragma unroll
        for (int mf = 0; mf < MF; ++mf)
            ah[mf] = *(const bf16x8*)&Ah[wm + mf * 16 + lr][lk];
#pragma unroll
        for (int nf = 0; nf < NF; ++nf) {
            bh[nf] = *(const bf16x8*)&Bh[wn + nf * 16 + lr][lk];
            bl[nf] = *(const bf16x8*)&Bl[wn + nf * 16 + lr][lk];
        }
#pragma unroll
        for (int mf = 0; mf < MF; ++mf)
#pragma unroll
            for (int nf = 0; nf < NF; ++nf) {
                acc[mf][nf] = __builtin_amdgcn_mfma_f32_16x16x32_bf16(ah[mf], bh[nf], acc[mf][nf], 0, 0, 0);
                acc[mf][nf] = __builtin_amdgcn_mfma_f32_16x16x32_bf16(ah[mf], bl[nf], acc[mf][nf], 0, 0, 0);
            }
        __syncthreads();
    }

#pragma unroll
    for (int mf = 0; mf < MF; ++mf) {
#pragma unroll
        for (int r = 0; r < 4; ++r) {
            int grow = row0 + wm + mf * 16 + (lane >> 4) * 4 + r;
            if (grow < M) {
                float dv = dinv[grow];
#pragma unroll
                for (int nf = 0; nf < NF; ++nf)
                    h_out[(size_t)grow * NOUT + wn + nf * 16 + lr] = f2bf(acc[mf][nf][r] * dv);
            }
        }
    }
}

// ---------------- aggregates (node-major bf16 h, 16 B/lane gathers, 8-deep MLP) ----------------
// CSR rows are padded to x4 with sentinel src=N (zero row) -> no serial 1-tail.

__device__ inline void acc8(float* a, uint4 v) {
    a[0] += __uint_as_float(v.x << 16);
    a[1] += __uint_as_float(v.x & 0xFFFF0000u);
    a[2] += __uint_as_float(v.y << 16);
    a[3] += __uint_as_float(v.y & 0xFFFF0000u);
    a[4] += __uint_as_float(v.z << 16);
    a[5] += __uint_as_float(v.z & 0xFFFF0000u);
    a[6] += __uint_as_float(v.w << 16);
    a[7] += __uint_as_float(v.w & 0xFFFF0000u);
}

// OUT_BF16: store 8 bf16 (16 B) per thread (out feeds gemm2); else f32 pair of 16 B.
template<int C, bool RELU, bool OUT_BF16>
__global__ void k_aggregate(const int* __restrict__ row_ptr,
                            const int* __restrict__ row_end,
                            const int* __restrict__ csr,
                            const u16* __restrict__ h,
                            const float* __restrict__ dinv,
                            const float* __restrict__ bias,
                            void* __restrict__ out_v, int n) {
    constexpr int QSHIFT = (C == 128) ? 4 : 3;     // C/8 threads per node
    long long tid = (long long)blockIdx.x * blockDim.x + threadIdx.x;
    int node = (int)(tid >> QSHIFT);
    if (node >= n) return;
    int c = ((int)tid & ((1 << QSHIFT) - 1)) * 8;

    int k   = row_ptr[node];
    int end = row_end[node];

    float a[8] = {0.f, 0.f, 0.f, 0.f, 0.f, 0.f, 0.f, 0.f};
    acc8(a, *(const uint4*)&h[(size_t)node * C + c]);    // self-loop term

    for (; k + 8 <= end; k += 8) {                        // 8 gathers in flight
        int s0 = csr[k],     s1 = csr[k + 1], s2 = csr[k + 2], s3 = csr[k + 3];
        int s4 = csr[k + 4], s5 = csr[k + 5], s6 = csr[k + 6], s7 = csr[k + 7];
        uint4 v0 = *(const uint4*)&h[(size_t)s0 * C + c];
        uint4 v1 = *(const uint4*)&h[(size_t)s1 * C + c];
        uint4 v2 = *(const uint4*)&h[(size_t)s2 * C + c];
        uint4 v3 = *(const uint4*)&h[(size_t)s3 * C + c];
        uint4 v4 = *(const uint4*)&h[(size_t)s4 * C + c];
        uint4 v5 = *(const uint4*)&h[(size_t)s5 * C + c];
        uint4 v6 = *(const uint4*)&h[(size_t)s6 * C + c];
        uint4 v7 = *(const uint4*)&h[(size_t)s7 * C + c];
        acc8(a, v0); acc8(a, v1); acc8(a, v2); acc8(a, v3);
        acc8(a, v4); acc8(a, v5); acc8(a, v6); acc8(a, v7);
    }
    if (k + 4 <= end) {                                   // exact (padded to x4)
        int s0 = csr[k], s1 = csr[k + 1], s2 = csr[k + 2], s3 = csr[k + 3];
        uint4 v0 = *(const uint4*)&h[(size_t)s0 * C + c];
        uint4 v1 = *(const uint4*)&h[(size_t)s1 * C + c];
        uint4 v2 = *(const uint4*)&h[(size_t)s2 * C + c];
        uint4 v3 = *(const uint4*)&h[(size_t)s3 * C + c];
        acc8(a, v0); acc8(a, v1); acc8(a, v2); acc8(a, v3);
        k += 4;
    }
    for (; k < end; ++k) {                                // dead unless clamped build
        int s0 = csr[k];
        acc8(a, *(const uint4*)&h[(size_t)s0 * C + c]);
    }

    float dvn = dinv[node];
    float4 b0 = *(const float4*)&bias[c];
    float4 b1 = *(const float4*)&bias[c + 4];
    float o[8];
    o[0] = fmaf(a[0], dvn, b0.x);
    o[1] = fmaf(a[1], dvn, b0.y);
    o[2] = fmaf(a[2], dvn, b0.z);
    o[3] = fmaf(a[3], dvn, b0.w);
    o[4] = fmaf(a[4], dvn, b1.x);
    o[5] = fmaf(a[5], dvn, b1.y);
    o[6] = fmaf(a[6], dvn, b1.z);
    o[7] = fmaf(a[7], dvn, b1.w);
    if (RELU) {
#pragma unroll
        for (int j = 0; j < 8; ++j) o[j] = fmaxf(o[j], 0.f);
    }
    if (OUT_BF16) {
        u16 r[8];
#pragma unroll
        for (int j = 0; j < 8; ++j) r[j] = f2bf(o[j]);
        *(uint4*)&((u16*)out_v)[(size_t)node * C + c] = *(const uint4*)r;
    } else {
        float* out = (float*)out_v;
        *(f32x4*)&out[(size_t)node * C + c]     = *(const f32x4*)&o[0];
        *(f32x4*)&out[(size_t)node * C + c + 4] = *(const f32x4*)&o[4];
    }
}

// ---------------- launch ----------------

extern "C" void kernel_launch(void* const* d_in, const int* in_sizes, int n_in,
                              void* d_out, int out_size, void* d_ws, size_t ws_size,
                              hipStream_t stream) {
    const float* x   = (const float*)d_in[0];
    const int*   ei  = (const int*)d_in[1];     // harness delivers integers as int32
    const float* W1  = (const float*)d_in[2];
    const float* b1  = (const float*)d_in[3];
    const float* W2  = (const float*)d_in[4];
    const float* b2  = (const float*)d_in[5];
    float*       out = (float*)d_out;

    const int N = in_sizes[0] / IN_CH;
    const int E = in_sizes[1] / 2;
    const int* esrc = ei;
    const int* edst = ei + E;

    const int NSB = (N + SBN - 1) / SBN;   // super-buckets (98)
    const int NBB = (E + EPB - 1) / EPB;   // bin blocks (196)
    const int GB  = (N + 63) / 64;         // gemm blocks (BM=64)

    char* ws = (char*)d_ws;
    int*   sb_fill = (int*)ws;    ws += (size_t)((NSB + 31) & ~31) * 4;
    u32*   sbe     = (u32*)ws;    ws += (size_t)NSB * SB_CAP * 4;   // SB-grouped edges
    int*   csr     = (int*)ws;    ws += (size_t)NSB * SB_CAP * 4;   // slotted padded CSR
    int*   row_ptr = (int*)ws;    ws += (size_t)N * 4;
    int*   row_end = (int*)ws;    ws += (size_t)N * 4;
    float* dinv    = (float*)ws;  ws += (size_t)N * 4;
    // NOTE: k_gemm2's tail-block gload streams up to ~16KB past out1/W2 tables
    // (OOB rows masked in epilogue) — keep each followed by more ws.
    u16*   W1h     = (u16*)ws;    ws += (size_t)HID * IN_CH * 2;
    u16*   W1l     = (u16*)ws;    ws += (size_t)HID * IN_CH * 2;
    u16*   W2h     = (u16*)ws;    ws += (size_t)LAT * HID * 2;
    u16*   W2l     = (u16*)ws;    ws += (size_t)LAT * HID * 2;
    u16*   h1      = (u16*)ws;    ws += (size_t)(N + 1) * HID * 2; // +1: zero sentinel row
    u16*   out1    = (u16*)ws;    ws += (size_t)N * HID * 2;       // agg1 out (bf16, GEMM2's A)
    u16*   h2      = (u16*)ws;    ws += (size_t)(N + 1) * LAT * 2; // +1: zero sentinel row

    dim3 blk(256);

    // ---- prep (merged zero + W splits + sentinel rows) ----
    k_prep<<<(HID * IN_CH + 255) / 256, blk, 0, stream>>>(
        W1, W1h, W1l, W2, W2h, W2l, sb_fill, NSB,
        h1 + (size_t)N * HID, h2 + (size_t)N * LAT);

    // ---- coalesced-write CSR build (padded rows) ----
    k_bin_sb<<<NBB, dim3(512), 0, stream>>>(esrc, edst, sb_fill, sbe, E, NSB);
    k_sbsort<<<NSB * 2, dim3(512), 0, stream>>>(sb_fill, sbe, csr, row_ptr, row_end, dinv, N);

    // ---- layer 1: 256 -> 128, relu ----
    k_gemm1<<<GB, dim3(512), 0, stream>>>(x, W1h, W1l, dinv, h1, N);
    {
        long long tot = (long long)N * 16;
        k_aggregate<HID, true, true><<<(unsigned)((tot + 255) / 256), blk, 0, stream>>>(
            row_ptr, row_end, csr, h1, dinv, b1, out1, N);
    }

    // ---- layer 2: 128 -> 64 ----
    k_gemm2<<<GB, dim3(512), 0, stream>>>(out1, W2h, W2l, dinv, h2, N);
    {
        long long tot = (long long)N * 8;
        k_aggregate<LAT, false, false><<<(unsigned)((tot + 255) / 256), blk, 0, stream>>>(
            row_ptr, row_end, csr, h2, dinv, b2, out, N);
    }
}